// Round 5
// baseline (174.144 us; speedup 1.0000x reference)
//
#include <hip/hip_runtime.h>

#define SBD   384
#define NCATS 64
#define EMB   48
#define HT    256
#define HC    128
#define MB    64     // books per block

typedef __attribute__((ext_vector_type(8))) short short8;
typedef __attribute__((ext_vector_type(4))) float f32x4;

__device__ __forceinline__ short f2bf(float x) {
    union { float f; unsigned u; } v; v.f = x;
    unsigned r = v.u + 0x7FFF + ((v.u >> 16) & 1);   // RNE
    return (short)(r >> 16);
}

__device__ __forceinline__ short8 cvt8(float4 a, float4 b) {
    short8 h;
    h[0] = f2bf(a.x); h[1] = f2bf(a.y); h[2] = f2bf(a.z); h[3] = f2bf(a.w);
    h[4] = f2bf(b.x); h[5] = f2bf(b.y); h[6] = f2bf(b.z); h[7] = f2bf(b.w);
    return h;
}

// ---------------------------------------------------------------------------
// Prep: bf16 LINEAR frag images, [n][k] contiguous-k rows.
// iT1: 12 chunks of [256n][32k] (16KB each); iT2 [48][256]; iC1 [128][64];
// iC2 [48][128].
// ---------------------------------------------------------------------------
__global__ void prep_weights(const float* __restrict__ Wt1, const float* __restrict__ Wt2,
                             const float* __restrict__ Wc1, const float* __restrict__ Wc2,
                             char* __restrict__ iT1, char* __restrict__ iT2,
                             char* __restrict__ iC1, char* __restrict__ iC2) {
    int t = blockIdx.x * blockDim.x + threadIdx.x;
    int stride = gridDim.x * blockDim.x;
    for (int g = t; g < 256 * 48; g += stride) {       // Wt1 [384k][256n]
        int n = g / 48, k0 = (g - n * 48) * 8;
        int c = k0 >> 5, kin = k0 & 31;
        short8 v;
        #pragma unroll
        for (int j = 0; j < 8; ++j) v[j] = f2bf(Wt1[(size_t)(k0 + j) * HT + n]);
        *(short8*)(iT1 + (size_t)c * 16384 + n * 64 + kin * 2) = v;
    }
    for (int g = t; g < 48 * 32; g += stride) {        // Wt2 [256k][48n]
        int n = g / 32, k0 = (g - n * 32) * 8;
        short8 v;
        #pragma unroll
        for (int j = 0; j < 8; ++j) v[j] = f2bf(Wt2[(size_t)(k0 + j) * EMB + n]);
        *(short8*)(iT2 + n * 512 + k0 * 2) = v;
    }
    for (int g = t; g < 128 * 8; g += stride) {        // Wc1 [64k][128n]
        int n = g / 8, k0 = (g - n * 8) * 8;
        short8 v;
        #pragma unroll
        for (int j = 0; j < 8; ++j) v[j] = f2bf(Wc1[(size_t)(k0 + j) * HC + n]);
        *(short8*)(iC1 + n * 128 + k0 * 2) = v;
    }
    for (int g = t; g < 48 * 16; g += stride) {        // Wc2 [128k][48n]
        int n = g / 16, k0 = (g - n * 16) * 8;
        short8 v;
        #pragma unroll
        for (int j = 0; j < 8; ++j) v[j] = f2bf(Wc2[(size_t)(k0 + j) * EMB + n]);
        *(short8*)(iC2 + n * 256 + k0 * 2) = v;
    }
}

// ---------------------------------------------------------------------------
// Encoder. Key change vs R4: NO barriers in the streaming/compute path.
//  - whole A tile (64x384 bf16, 48KB swz) staged up front, ONE __syncthreads
//  - L1: 12 k-steps, zero barriers; B-frags from L2-resident images (2-slot ring)
//  - mh never touches LDS (C1 A-frags direct from global, issued early)
//  - H1c is wave-local rows -> lgkmcnt only
// LDS map (80KB, 2 blocks/CU): A [64][384] swz @0 ; H1t [64][256] swz @48K;
//   H1c [64][128] swz @0 (A dead by then).
// ---------------------------------------------------------------------------
__global__ __launch_bounds__(256, 2) void encode_books_mfma(
    const float* __restrict__ sbert, const float* __restrict__ mh,
    const char* __restrict__ iT1, const char* __restrict__ iT2,
    const char* __restrict__ iC1, const char* __restrict__ iC2,
    const float* __restrict__ bt1, const float* __restrict__ bt2,
    const float* __restrict__ bc1, const float* __restrict__ bc2,
    float* __restrict__ E, int nbooks)
{
    __shared__ char lds[81920];

    const int t  = threadIdx.x;
    const int w  = t >> 6;
    const int l  = t & 63;
    const int lr = l & 15;
    const int lg = l >> 4;
    const int book0 = blockIdx.x * MB;
    const int wm = w >> 1, wn = w & 1;      // L1 wave grid 2x2

    // ---- stage A: whole 64x384 tile, 24 float4/thread, one barrier ----
    const int srow = t >> 2, sk0 = (t & 3) * 8;
    const int sswz = (srow & 7) << 4;
    const size_t srb = (size_t)min(book0 + srow, nbooks - 1) * SBD + sk0;
    {
        float4 ar[12][2];
        #pragma unroll
        for (int c = 0; c < 12; ++c) {
            const float* p = sbert + srb + c * 32;
            ar[c][0] = *(const float4*)p;
            ar[c][1] = *(const float4*)(p + 4);
        }
        #pragma unroll
        for (int c = 0; c < 12; ++c)
            *(short8*)(lds + ((srow * 768 + c * 64 + sk0 * 2) ^ sswz)) = cvt8(ar[c][0], ar[c][1]);
    }

    // B chunk-0 prefetch (L2) before the barrier
    const char* bb1 = iT1 + wn * 8192 + lr * 64 + lg * 16;
    short8 bb[2][8];
    #pragma unroll
    for (int nt = 0; nt < 8; ++nt) bb[0][nt] = *(const short8*)(bb1 + nt * 1024);

    __syncthreads();

    // ---- L1 txt: 12 k-steps, NO barriers ----
    f32x4 acc[2][8];
    #pragma unroll
    for (int nt = 0; nt < 8; ++nt) {
        float b = bt1[wn * 128 + nt * 16 + lr];
        acc[0][nt] = (f32x4){b, b, b, b};
        acc[1][nt] = (f32x4){b, b, b, b};
    }
    const int ar0 = wm * 32 + lr, ar1 = wm * 32 + 16 + lr;
    const int aswz0 = (ar0 & 7) << 4, aswz1 = (ar1 & 7) << 4;

    #pragma unroll
    for (int c = 0; c < 12; ++c) {
        if (c + 1 < 12) {
            #pragma unroll
            for (int nt = 0; nt < 8; ++nt)
                bb[(c + 1) & 1][nt] = *(const short8*)(bb1 + (c + 1) * 16384 + nt * 1024);
        }
        short8 af0 = *(const short8*)(lds + ((ar0 * 768 + c * 64 + lg * 16) ^ aswz0));
        short8 af1 = *(const short8*)(lds + ((ar1 * 768 + c * 64 + lg * 16) ^ aswz1));
        #pragma unroll
        for (int nt = 0; nt < 8; ++nt) {
            acc[0][nt] = __builtin_amdgcn_mfma_f32_16x16x32_bf16(af0, bb[c & 1][nt], acc[0][nt], 0, 0, 0);
            acc[1][nt] = __builtin_amdgcn_mfma_f32_16x16x32_bf16(af1, bb[c & 1][nt], acc[1][nt], 0, 0, 0);
        }
    }

    // ---- H1t relu->bf16 -> LDS @48K ----
    #pragma unroll
    for (int mt = 0; mt < 2; ++mt)
        #pragma unroll
        for (int nt = 0; nt < 8; ++nt)
            #pragma unroll
            for (int r = 0; r < 4; ++r) {
                int row = wm * 32 + mt * 16 + lg * 4 + r;
                int col = wn * 128 + nt * 16 + lr;
                *(unsigned short*)(lds + 49152 + ((row * 512 + col * 2) ^ ((row & 7) << 4))) =
                    (unsigned short)f2bf(fmaxf(acc[mt][nt][r], 0.f));
            }

    // issue mh A-frag loads EARLY (HBM latency hides under L2txt)
    const int arow = w * 16 + lr;
    const size_t mrb = (size_t)min(book0 + arow, nbooks - 1) * NCATS;
    float4 mf[2][2];
    #pragma unroll
    for (int ks = 0; ks < 2; ++ks) {
        const float* p = mh + mrb + lg * 8 + ks * 32;
        mf[ks][0] = *(const float4*)p;
        mf[ks][1] = *(const float4*)(p + 4);
    }

    asm volatile("s_waitcnt lgkmcnt(0)" ::: "memory");
    __builtin_amdgcn_sched_barrier(0);
    __builtin_amdgcn_s_barrier();

    // ---- L2 txt: H1t[64][256] @ Wt2 ----
    const int aswz = (lr & 7) << 4;
    f32x4 acct[3];
    #pragma unroll
    for (int nt = 0; nt < 3; ++nt) { float b = bt2[nt * 16 + lr]; acct[nt] = (f32x4){b, b, b, b}; }
    #pragma unroll
    for (int ks = 0; ks < 8; ++ks) {
        short8 af = *(const short8*)(lds + 49152 + ((arow * 512 + (lg * 8 + ks * 32) * 2) ^ aswz));
        #pragma unroll
        for (int nt = 0; nt < 3; ++nt) {
            short8 bf = *(const short8*)(iT2 + (nt * 16 + lr) * 512 + (lg * 8 + ks * 32) * 2);
            acct[nt] = __builtin_amdgcn_mfma_f32_16x16x32_bf16(af, bf, acct[nt], 0, 0, 0);
        }
    }

    // ---- L1 cat: mh direct from regs @ Wc1 ----
    f32x4 accc[8];
    #pragma unroll
    for (int nt = 0; nt < 8; ++nt) { float b = bc1[nt * 16 + lr]; accc[nt] = (f32x4){b, b, b, b}; }
    #pragma unroll
    for (int ks = 0; ks < 2; ++ks) {
        short8 af = cvt8(mf[ks][0], mf[ks][1]);
        #pragma unroll
        for (int nt = 0; nt < 8; ++nt) {
            short8 bf = *(const short8*)(iC1 + (nt * 16 + lr) * 128 + (lg * 8 + ks * 32) * 2);
            accc[nt] = __builtin_amdgcn_mfma_f32_16x16x32_bf16(af, bf, accc[nt], 0, 0, 0);
        }
    }

    // ---- H1c -> LDS @0 (wave-local rows: lgkmcnt only, no s_barrier) ----
    #pragma unroll
    for (int nt = 0; nt < 8; ++nt)
        #pragma unroll
        for (int r = 0; r < 4; ++r) {
            int row = w * 16 + lg * 4 + r, col = nt * 16 + lr;
            *(unsigned short*)(lds + ((row * 256 + col * 2) ^ ((row & 7) << 4))) =
                (unsigned short)f2bf(fmaxf(accc[nt][r], 0.f));
        }
    asm volatile("s_waitcnt lgkmcnt(0)" ::: "memory");
    __builtin_amdgcn_sched_barrier(0);

    // ---- L2 cat: H1c[64][128] @ Wc2 ----
    f32x4 acc2[3];
    #pragma unroll
    for (int nt = 0; nt < 3; ++nt) { float b = bc2[nt * 16 + lr]; acc2[nt] = (f32x4){b, b, b, b}; }
    #pragma unroll
    for (int ks = 0; ks < 4; ++ks) {
        short8 af = *(const short8*)(lds + ((arow * 256 + (lg * 8 + ks * 32) * 2) ^ aswz));
        #pragma unroll
        for (int nt = 0; nt < 3; ++nt) {
            short8 bf = *(const short8*)(iC2 + (nt * 16 + lr) * 256 + (lg * 8 + ks * 32) * 2);
            acc2[nt] = __builtin_amdgcn_mfma_f32_16x16x32_bf16(af, bf, acc2[nt], 0, 0, 0);
        }
    }

    // ---- combine, l2norm, store ----
    f32x4 comb[3];
    #pragma unroll
    for (int nt = 0; nt < 3; ++nt)
        #pragma unroll
        for (int r = 0; r < 4; ++r) comb[nt][r] = 3.0f * acc2[nt][r] + acct[nt][r];
    float rn[4];
    #pragma unroll
    for (int r = 0; r < 4; ++r) {
        float ss = comb[0][r] * comb[0][r] + comb[1][r] * comb[1][r] + comb[2][r] * comb[2][r];
        ss += __shfl_xor(ss, 1); ss += __shfl_xor(ss, 2);
        ss += __shfl_xor(ss, 4); ss += __shfl_xor(ss, 8);
        rn[r] = rsqrtf(fmaxf(ss, 1e-12f));
    }
    #pragma unroll
    for (int nt = 0; nt < 3; ++nt)
        #pragma unroll
        for (int r = 0; r < 4; ++r) {
            int grow = book0 + w * 16 + lg * 4 + r;
            if (grow < nbooks) E[(size_t)grow * EMB + nt * 16 + lr] = comb[nt][r] * rn[r];
        }
}

// ---------------------------------------------------------------------------
// Scoring: 16 lanes/sample, 3 dims/lane, shuffle-reduce.
// ---------------------------------------------------------------------------
__global__ __launch_bounds__(256) void score_kernel(
    const int* __restrict__ user_idx, const int* __restrict__ loc_idx,
    const int* __restrict__ pos_idx,  const int* __restrict__ neg_idx,
    const float* __restrict__ ucat, const float* __restrict__ utxt,
    const float* __restrict__ lcat, const float* __restrict__ ltxt,
    const float* __restrict__ E, float* __restrict__ out, int Bn)
{
    const int t    = threadIdx.x;
    const int lane = t & 15;
    const int s    = blockIdx.x * 16 + (t >> 4);
    if (s >= Bn) return;

    const int ui = user_idx[s];
    const int li = loc_idx[s];
    const int pi = pos_idx[s];
    const int ni = neg_idx[s];

    const int d0 = lane * 3;
    const float* uc = ucat + (size_t)ui * EMB + d0;
    const float* ut = utxt + (size_t)ui * EMB + d0;
    const float* lc = lcat + (size_t)li * EMB + d0;
    const float* lt = ltxt + (size_t)li * EMB + d0;
    const float* pp = E + (size_t)pi * EMB + d0;
    const float* nn = E + (size_t)ni * EMB + d0;

    float u0 = 3.0f * (uc[0] + lc[0]) + (ut[0] + lt[0]);
    float u1 = 3.0f * (uc[1] + lc[1]) + (ut[1] + lt[1]);
    float u2 = 3.0f * (uc[2] + lc[2]) + (ut[2] + lt[2]);

    float usq = u0 * u0 + u1 * u1 + u2 * u2;
    float ps  = u0 * pp[0] + u1 * pp[1] + u2 * pp[2];
    float ns  = u0 * nn[0] + u1 * nn[1] + u2 * nn[2];

    #pragma unroll
    for (int m = 1; m < 16; m <<= 1) {
        usq += __shfl_xor(usq, m);
        ps  += __shfl_xor(ps, m);
        ns  += __shfl_xor(ns, m);
    }

    if (lane == 0) {
        const float inv = rsqrtf(fmaxf(usq, 1e-12f)) * 20.0f;  // /TEMP
        out[2 * (size_t)s + 0] = ps * inv;
        out[2 * (size_t)s + 1] = ns * inv;
    }
}

extern "C" void kernel_launch(void* const* d_in, const int* in_sizes, int n_in,
                              void* d_out, int out_size, void* d_ws, size_t ws_size,
                              hipStream_t stream) {
    const int*   user_idx = (const int*)d_in[0];
    const int*   loc_idx  = (const int*)d_in[1];
    const int*   pos_idx  = (const int*)d_in[2];
    const int*   neg_idx  = (const int*)d_in[3];
    const float* ucat     = (const float*)d_in[4];
    const float* utxt     = (const float*)d_in[5];
    const float* lcat     = (const float*)d_in[6];
    const float* ltxt     = (const float*)d_in[7];
    const float* sbert    = (const float*)d_in[8];
    const float* mh       = (const float*)d_in[9];
    const float* Wc1      = (const float*)d_in[10];
    const float* bc1      = (const float*)d_in[11];
    const float* Wc2      = (const float*)d_in[12];
    const float* bc2      = (const float*)d_in[13];
    const float* Wt1      = (const float*)d_in[14];
    const float* bt1      = (const float*)d_in[15];
    const float* Wt2      = (const float*)d_in[16];
    const float* bt2      = (const float*)d_in[17];

    const int Bn     = in_sizes[0];
    const int nbooks = in_sizes[8] / SBD;

    char* ws = (char*)d_ws;
    float* E = (float*)ws;
    size_t off = (size_t)nbooks * EMB * 4;
    off = (off + 255) & ~(size_t)255;
    char* iT1 = ws + off; off += 196608;
    char* iT2 = ws + off; off += 24576;
    char* iC1 = ws + off; off += 16384;
    char* iC2 = ws + off; off += 12288;

    hipLaunchKernelGGL(prep_weights, dim3(64), dim3(256), 0, stream,
                       Wt1, Wt2, Wc1, Wc2, iT1, iT2, iC1, iC2);

    const int nblocksA = (nbooks + MB - 1) / MB;
    hipLaunchKernelGGL(encode_books_mfma, dim3(nblocksA), dim3(256), 0, stream,
                       sbert, mh, iT1, iT2, iC1, iC2, bt1, bt2, bc1, bc2, E, nbooks);

    const int nblocksB = (Bn + 15) / 16;
    hipLaunchKernelGGL(score_kernel, dim3(nblocksB), dim3(256), 0, stream,
                       user_idx, loc_idx, pos_idx, neg_idx,
                       ucat, utxt, lcat, ltxt, E, (float*)d_out, Bn);
}

// Round 6
// 153.711 us; speedup vs baseline: 1.1329x; 1.1329x over previous
//
#include <hip/hip_runtime.h>

#define SBD   384
#define NCATS 64
#define EMB   48
#define HT    256
#define HC    128
#define MB    64     // books per block

typedef __attribute__((ext_vector_type(8))) short short8;
typedef __attribute__((ext_vector_type(4))) float f32x4;

__device__ __forceinline__ short f2bf(float x) {
    union { float f; unsigned u; } v; v.f = x;
    unsigned r = v.u + 0x7FFF + ((v.u >> 16) & 1);   // RNE
    return (short)(r >> 16);
}

__device__ __forceinline__ short8 cvt8(float4 a, float4 b) {
    short8 h;
    h[0] = f2bf(a.x); h[1] = f2bf(a.y); h[2] = f2bf(a.z); h[3] = f2bf(a.w);
    h[4] = f2bf(b.x); h[5] = f2bf(b.y); h[6] = f2bf(b.z); h[7] = f2bf(b.w);
    return h;
}

// ---------------------------------------------------------------------------
// Prep: bf16 LINEAR frag images, [n][k] rows with contiguous k.
// iT1 [256][384]; iT2 [48][256]; iC1 [128][64]; iC2 [48][128].
// ---------------------------------------------------------------------------
__global__ void prep_weights(const float* __restrict__ Wt1, const float* __restrict__ Wt2,
                             const float* __restrict__ Wc1, const float* __restrict__ Wc2,
                             char* __restrict__ iT1, char* __restrict__ iT2,
                             char* __restrict__ iC1, char* __restrict__ iC2) {
    int t = blockIdx.x * blockDim.x + threadIdx.x;
    int stride = gridDim.x * blockDim.x;
    for (int g = t; g < 256 * 48; g += stride) {       // Wt1 [384k][256n]
        int n = g / 48, k0 = (g - n * 48) * 8;
        short8 v;
        #pragma unroll
        for (int j = 0; j < 8; ++j) v[j] = f2bf(Wt1[(size_t)(k0 + j) * HT + n]);
        *(short8*)(iT1 + (size_t)n * 768 + k0 * 2) = v;
    }
    for (int g = t; g < 48 * 32; g += stride) {        // Wt2 [256k][48n]
        int n = g / 32, k0 = (g - n * 32) * 8;
        short8 v;
        #pragma unroll
        for (int j = 0; j < 8; ++j) v[j] = f2bf(Wt2[(size_t)(k0 + j) * EMB + n]);
        *(short8*)(iT2 + n * 512 + k0 * 2) = v;
    }
    for (int g = t; g < 128 * 8; g += stride) {        // Wc1 [64k][128n]
        int n = g / 8, k0 = (g - n * 8) * 8;
        short8 v;
        #pragma unroll
        for (int j = 0; j < 8; ++j) v[j] = f2bf(Wc1[(size_t)(k0 + j) * HC + n]);
        *(short8*)(iC1 + n * 128 + k0 * 2) = v;
    }
    for (int g = t; g < 48 * 16; g += stride) {        // Wc2 [128k][48n]
        int n = g / 16, k0 = (g - n * 16) * 8;
        short8 v;
        #pragma unroll
        for (int j = 0; j < 8; ++j) v[j] = f2bf(Wc2[(size_t)(k0 + j) * EMB + n]);
        *(short8*)(iC2 + n * 256 + k0 * 2) = v;
    }
}

// ---------------------------------------------------------------------------
// Encoder v6: wave-private streaming, barrier-free main loop.
// 512 threads = 8 waves, 64 books/block.
// L1: wave w owns ALL 64 rows x cols [w*32, w*32+32): per k-step only
//   2 B-frag reg loads (dist-3 ring, 4 slots) + 4 ds_read_b128 (A) + 8 MFMA.
// LDS 48KB total (3 would fit but VGPR caps at 2 blocks/CU = 4 waves/SIMD):
//   A [64][384] bf16 swz @0 (48K); after L1: H1t [64][256] @0 (32K),
//   H1c [64][128] @32K (16K) -- both overlap dead A.
// Tail: waves 0-3 L2txt+L2cat+norm (16 rows each, wave-local norm);
//       waves 4-7 cat-L1 from early mh reg loads -> H1c.
// Barriers per block: 3 (+1 prestage). None inside the k-loop.
// ---------------------------------------------------------------------------
__global__ __launch_bounds__(512, 4) void encode_books_mfma(
    const float* __restrict__ sbert, const float* __restrict__ mh,
    const char* __restrict__ iT1, const char* __restrict__ iT2,
    const char* __restrict__ iC1, const char* __restrict__ iC2,
    const float* __restrict__ bt1, const float* __restrict__ bt2,
    const float* __restrict__ bc1, const float* __restrict__ bc2,
    float* __restrict__ E, int nbooks)
{
    __shared__ char lds[49152];

    const int t  = threadIdx.x;
    const int w  = t >> 6;
    const int l  = t & 63;
    const int lr = l & 15;
    const int lg = l >> 4;
    const int book0 = blockIdx.x * MB;

    // ---- mh early loads (waves 4-7 only; hidden under everything) ----
    float4 mf[4];
    if (w >= 4) {
        const int mrow = (w - 4) * 16 + lr;
        const float* mp = mh + (size_t)min(book0 + mrow, nbooks - 1) * NCATS + lg * 8;
        mf[0] = *(const float4*)(mp);
        mf[1] = *(const float4*)(mp + 4);
        mf[2] = *(const float4*)(mp + 32);
        mf[3] = *(const float4*)(mp + 36);
    }

    // ---- A prestage: 12 float4/thread, all issued before any use ----
    {
        const int row = t >> 3, kseg = (t & 7) * 48;
        const float* ap = sbert + (size_t)min(book0 + row, nbooks - 1) * SBD + kseg;
        float4 f[12];
        #pragma unroll
        for (int j = 0; j < 12; ++j) f[j] = *(const float4*)(ap + 4 * j);
        #pragma unroll
        for (int i = 0; i < 6; ++i)
            *(short8*)(lds + ((row * 768 + (kseg + 8 * i) * 2) ^ ((row & 7) << 4))) =
                cvt8(f[2 * i], f[2 * i + 1]);
    }

    // ---- B ring prologue (chunks 0..2) ----
    const char* bfr = iT1 + (size_t)(w * 32 + lr) * 768 + lg * 16;
    short8 bb[4][2];
    #pragma unroll
    for (int d = 0; d < 3; ++d)
        #pragma unroll
        for (int nt = 0; nt < 2; ++nt)
            bb[d][nt] = *(const short8*)(bfr + d * 64 + nt * 12288);

    f32x4 acc[4][2];
    #pragma unroll
    for (int nt = 0; nt < 2; ++nt) {
        float b = bt1[w * 32 + nt * 16 + lr];
        #pragma unroll
        for (int a = 0; a < 4; ++a) acc[a][nt] = (f32x4){b, b, b, b};
    }

    __syncthreads();

    // ---- L1 txt: 12 k-steps, NO barriers, NO vmcnt(0) ----
    const int aswz = (lr & 7) << 4;
    #pragma unroll
    for (int c = 0; c < 12; ++c) {
        if (c < 9) {
            #pragma unroll
            for (int nt = 0; nt < 2; ++nt)
                bb[(c + 3) & 3][nt] = *(const short8*)(bfr + (c + 3) * 64 + nt * 12288);
        }
        short8 af[4];
        #pragma unroll
        for (int a = 0; a < 4; ++a)
            af[a] = *(const short8*)(lds + (((16 * a + lr) * 768 + c * 64 + lg * 16) ^ aswz));
        #pragma unroll
        for (int a = 0; a < 4; ++a)
            #pragma unroll
            for (int nt = 0; nt < 2; ++nt)
                acc[a][nt] = __builtin_amdgcn_mfma_f32_16x16x32_bf16(af[a], bb[c & 3][nt], acc[a][nt], 0, 0, 0);
    }

    __syncthreads();   // everyone done reading A; its LDS region can be reused

    // ---- H1t relu->bf16 -> LDS @0 [64][256] swz (all 8 waves write their cols) ----
    #pragma unroll
    for (int a = 0; a < 4; ++a)
        #pragma unroll
        for (int nt = 0; nt < 2; ++nt)
            #pragma unroll
            for (int r = 0; r < 4; ++r) {
                int row = 16 * a + lg * 4 + r;
                int col = w * 32 + nt * 16 + lr;
                *(unsigned short*)(lds + ((row * 512 + col * 2) ^ ((row & 7) << 4))) =
                    (unsigned short)f2bf(fmaxf(acc[a][nt][r], 0.f));
            }

    // ---- waves 4-7: cat L1 from mh regs -> H1c @32K [64][128] swz ----
    if (w >= 4) {
        f32x4 accc[8];
        #pragma unroll
        for (int nt = 0; nt < 8; ++nt) { float b = bc1[nt * 16 + lr]; accc[nt] = (f32x4){b, b, b, b}; }
        #pragma unroll
        for (int ks = 0; ks < 2; ++ks) {
            short8 af = cvt8(mf[2 * ks], mf[2 * ks + 1]);
            #pragma unroll
            for (int nt = 0; nt < 8; ++nt) {
                short8 bf = *(const short8*)(iC1 + (nt * 16 + lr) * 128 + (lg * 8 + ks * 32) * 2);
                accc[nt] = __builtin_amdgcn_mfma_f32_16x16x32_bf16(af, bf, accc[nt], 0, 0, 0);
            }
        }
        #pragma unroll
        for (int nt = 0; nt < 8; ++nt)
            #pragma unroll
            for (int r = 0; r < 4; ++r) {
                int row = (w - 4) * 16 + lg * 4 + r;
                int col = nt * 16 + lr;
                *(unsigned short*)(lds + 32768 + ((row * 256 + col * 2) ^ ((row & 7) << 4))) =
                    (unsigned short)f2bf(fmaxf(accc[nt][r], 0.f));
            }
    }

    __syncthreads();
    if (w >= 4) return;

    // ---- waves 0-3: rows w*16..+16 ----
    const int arow = w * 16 + lr;
    const int aswz2 = (lr & 7) << 4;

    // L2 txt: H1t[64][256] @ Wt2
    f32x4 acct[3];
    #pragma unroll
    for (int nt = 0; nt < 3; ++nt) { float b = bt2[nt * 16 + lr]; acct[nt] = (f32x4){b, b, b, b}; }
    #pragma unroll
    for (int ks = 0; ks < 8; ++ks) {
        short8 af = *(const short8*)(lds + ((arow * 512 + (lg * 8 + ks * 32) * 2) ^ aswz2));
        #pragma unroll
        for (int nt = 0; nt < 3; ++nt) {
            short8 bf = *(const short8*)(iT2 + (nt * 16 + lr) * 512 + (lg * 8 + ks * 32) * 2);
            acct[nt] = __builtin_amdgcn_mfma_f32_16x16x32_bf16(af, bf, acct[nt], 0, 0, 0);
        }
    }

    // L2 cat: H1c[64][128] @ Wc2
    f32x4 acc2[3];
    #pragma unroll
    for (int nt = 0; nt < 3; ++nt) { float b = bc2[nt * 16 + lr]; acc2[nt] = (f32x4){b, b, b, b}; }
    #pragma unroll
    for (int ks = 0; ks < 4; ++ks) {
        short8 af = *(const short8*)(lds + 32768 + ((arow * 256 + (lg * 8 + ks * 32) * 2) ^ aswz2));
        #pragma unroll
        for (int nt = 0; nt < 3; ++nt) {
            short8 bf = *(const short8*)(iC2 + (nt * 16 + lr) * 256 + (lg * 8 + ks * 32) * 2);
            acc2[nt] = __builtin_amdgcn_mfma_f32_16x16x32_bf16(af, bf, acc2[nt], 0, 0, 0);
        }
    }

    // combine, l2norm (wave-local), store E
    f32x4 comb[3];
    #pragma unroll
    for (int nt = 0; nt < 3; ++nt)
        #pragma unroll
        for (int r = 0; r < 4; ++r) comb[nt][r] = 3.0f * acc2[nt][r] + acct[nt][r];
    float rn[4];
    #pragma unroll
    for (int r = 0; r < 4; ++r) {
        float ss = comb[0][r] * comb[0][r] + comb[1][r] * comb[1][r] + comb[2][r] * comb[2][r];
        ss += __shfl_xor(ss, 1); ss += __shfl_xor(ss, 2);
        ss += __shfl_xor(ss, 4); ss += __shfl_xor(ss, 8);
        rn[r] = rsqrtf(fmaxf(ss, 1e-12f));
    }
    #pragma unroll
    for (int nt = 0; nt < 3; ++nt)
        #pragma unroll
        for (int r = 0; r < 4; ++r) {
            int grow = book0 + w * 16 + lg * 4 + r;
            if (grow < nbooks) E[(size_t)grow * EMB + nt * 16 + lr] = comb[nt][r] * rn[r];
        }
}

// ---------------------------------------------------------------------------
// Scoring: 16 lanes/sample, 3 dims/lane, shuffle-reduce.
// ---------------------------------------------------------------------------
__global__ __launch_bounds__(256) void score_kernel(
    const int* __restrict__ user_idx, const int* __restrict__ loc_idx,
    const int* __restrict__ pos_idx,  const int* __restrict__ neg_idx,
    const float* __restrict__ ucat, const float* __restrict__ utxt,
    const float* __restrict__ lcat, const float* __restrict__ ltxt,
    const float* __restrict__ E, float* __restrict__ out, int Bn)
{
    const int t    = threadIdx.x;
    const int lane = t & 15;
    const int s    = blockIdx.x * 16 + (t >> 4);
    if (s >= Bn) return;

    const int ui = user_idx[s];
    const int li = loc_idx[s];
    const int pi = pos_idx[s];
    const int ni = neg_idx[s];

    const int d0 = lane * 3;
    const float* uc = ucat + (size_t)ui * EMB + d0;
    const float* ut = utxt + (size_t)ui * EMB + d0;
    const float* lc = lcat + (size_t)li * EMB + d0;
    const float* lt = ltxt + (size_t)li * EMB + d0;
    const float* pp = E + (size_t)pi * EMB + d0;
    const float* nn = E + (size_t)ni * EMB + d0;

    float u0 = 3.0f * (uc[0] + lc[0]) + (ut[0] + lt[0]);
    float u1 = 3.0f * (uc[1] + lc[1]) + (ut[1] + lt[1]);
    float u2 = 3.0f * (uc[2] + lc[2]) + (ut[2] + lt[2]);

    float usq = u0 * u0 + u1 * u1 + u2 * u2;
    float ps  = u0 * pp[0] + u1 * pp[1] + u2 * pp[2];
    float ns  = u0 * nn[0] + u1 * nn[1] + u2 * nn[2];

    #pragma unroll
    for (int m = 1; m < 16; m <<= 1) {
        usq += __shfl_xor(usq, m);
        ps  += __shfl_xor(ps, m);
        ns  += __shfl_xor(ns, m);
    }

    if (lane == 0) {
        const float inv = rsqrtf(fmaxf(usq, 1e-12f)) * 20.0f;  // /TEMP
        out[2 * (size_t)s + 0] = ps * inv;
        out[2 * (size_t)s + 1] = ns * inv;
    }
}

extern "C" void kernel_launch(void* const* d_in, const int* in_sizes, int n_in,
                              void* d_out, int out_size, void* d_ws, size_t ws_size,
                              hipStream_t stream) {
    const int*   user_idx = (const int*)d_in[0];
    const int*   loc_idx  = (const int*)d_in[1];
    const int*   pos_idx  = (const int*)d_in[2];
    const int*   neg_idx  = (const int*)d_in[3];
    const float* ucat     = (const float*)d_in[4];
    const float* utxt     = (const float*)d_in[5];
    const float* lcat     = (const float*)d_in[6];
    const float* ltxt     = (const float*)d_in[7];
    const float* sbert    = (const float*)d_in[8];
    const float* mh       = (const float*)d_in[9];
    const float* Wc1      = (const float*)d_in[10];
    const float* bc1      = (const float*)d_in[11];
    const float* Wc2      = (const float*)d_in[12];
    const float* bc2      = (const float*)d_in[13];
    const float* Wt1      = (const float*)d_in[14];
    const float* bt1      = (const float*)d_in[15];
    const float* Wt2      = (const float*)d_in[16];
    const float* bt2      = (const float*)d_in[17];

    const int Bn     = in_sizes[0];
    const int nbooks = in_sizes[8] / SBD;

    char* ws = (char*)d_ws;
    float* E = (float*)ws;
    size_t off = (size_t)nbooks * EMB * 4;
    off = (off + 255) & ~(size_t)255;
    char* iT1 = ws + off; off += 196608;
    char* iT2 = ws + off; off += 24576;
    char* iC1 = ws + off; off += 16384;
    char* iC2 = ws + off; off += 12288;

    hipLaunchKernelGGL(prep_weights, dim3(64), dim3(256), 0, stream,
                       Wt1, Wt2, Wc1, Wc2, iT1, iT2, iC1, iC2);

    const int nblocksA = (nbooks + MB - 1) / MB;
    hipLaunchKernelGGL(encode_books_mfma, dim3(nblocksA), dim3(512), 0, stream,
                       sbert, mh, iT1, iT2, iC1, iC2, bt1, bt2, bc1, bc2, E, nbooks);

    const int nblocksB = (Bn + 15) / 16;
    hipLaunchKernelGGL(score_kernel, dim3(nblocksB), dim3(256), 0, stream,
                       user_idx, loc_idx, pos_idx, neg_idx,
                       ucat, utxt, lcat, ltxt, E, (float*)d_out, Bn);
}